// Round 4
// baseline (476.014 us; speedup 1.0000x reference)
//
#include <hip/hip_runtime.h>

// DynamicGraphAttention: B=16, L=256, D=128, F_IN=64, F_OUT=64
// v8 = v7 with the phase-C P-tile LDS round trip eliminated: each thread now
// builds P directly in MFMA A-fragment layout (rows w*32+m16/+16, cols
// j0+g*8+q), so P goes build -> f16 -> pa[] -> MFMA entirely in registers.
// Deletes 2 LDS writes + 2 b128 reads + lgkm waits from the per-tile critical
// chain and all P-tile bank conflicts. Row sums via shfl_xor(16/32) over the
// g-lane bits + one small sL exchange for the epilogue's D-layout rows.
constexpr int D_   = 128;
constexpr int FIN  = 64;
constexpr int FOUT = 64;
constexpr float ALPHA = 0.2f;

typedef _Float16 f16x8 __attribute__((ext_vector_type(8)));
typedef float    f32x4 __attribute__((ext_vector_type(4)));

__global__ __launch_bounds__(256, 4) void gat_kernel(
    const float* __restrict__ hg, const int* __restrict__ adjg,
    const float* __restrict__ Wg, const float* __restrict__ ag,
    float* __restrict__ outg)
{
    // sX (16KB): phase A = h f16 [d][64] swz((d&7)<<4); phase B/C = WhT f16 [o][128] swz((o&7)<<4)
    __shared__ __align__(16) unsigned short sX[128 * 64];
    // sPt (8KB): W^T f16 [o][64] swz((o&7)<<4) (phase A only; P no longer staged)
    __shared__ __align__(16) unsigned short sPt[64 * 64];
    __shared__ __align__(16) float sA[2 * FOUT];
    __shared__ float sEi[D_];
    __shared__ __align__(16) float sEj[D_];
    __shared__ float sL[D_];
    __shared__ float sMxW[4];

    const int tid  = threadIdx.x;
    const int lane = tid & 63;
    const int w    = tid >> 6;      // wave 0..3, owns output rows [w*32, w*32+32)
    const int g    = lane >> 4;     // k-group 0..3
    const int m16  = lane & 15;

    const long bl = blockIdx.x;
    const float* hp   = hg   + bl * (long)(D_ * FIN);
    const int*   adjp = adjg + bl * (long)(D_ * D_);
    float*       outp = outg + bl * (long)(D_ * FOUT);

    char* xb = (char*)sX;
    char* pb = (char*)sPt;

    // ---------------- stage: h -> sX f16 swz, W -> sPt transposed f16 swz, a -> sA ----------------
    {
        const float4* h4 = (const float4*)hp;
        #pragma unroll
        for (int k = 0; k < 8; ++k) {
            int idx = tid + 256 * k;          // float4 index in [0,2048)
            float4 v = h4[idx];
            int row = idx >> 4;               // 16 float4 per 64-float row
            int f   = (idx & 15) << 2;
            union { _Float16 h[4]; uint2 u; } cv;
            cv.h[0] = (_Float16)v.x; cv.h[1] = (_Float16)v.y;
            cv.h[2] = (_Float16)v.z; cv.h[3] = (_Float16)v.w;
            int off = (row * 128 + f * 2) ^ ((row & 7) << 4);
            *(uint2*)(xb + off) = cv.u;
        }
        // W: per-thread 4(f) x 4(o) register transpose, 8B conflict-free writes.
        {
            const int f0 = (tid & 15) * 4;
            const int o0 = (tid >> 4) * 4;
            float4 r0 = *(const float4*)&Wg[(f0 + 0) * 64 + o0];
            float4 r1 = *(const float4*)&Wg[(f0 + 1) * 64 + o0];
            float4 r2 = *(const float4*)&Wg[(f0 + 2) * 64 + o0];
            float4 r3 = *(const float4*)&Wg[(f0 + 3) * 64 + o0];
            float col[4][4] = {{r0.x, r1.x, r2.x, r3.x},
                               {r0.y, r1.y, r2.y, r3.y},
                               {r0.z, r1.z, r2.z, r3.z},
                               {r0.w, r1.w, r2.w, r3.w}};
            #pragma unroll
            for (int c = 0; c < 4; ++c) {
                int o = o0 + c;
                union { _Float16 h[4]; uint2 u; } cv;
                cv.h[0] = (_Float16)col[c][0]; cv.h[1] = (_Float16)col[c][1];
                cv.h[2] = (_Float16)col[c][2]; cv.h[3] = (_Float16)col[c][3];
                int off = (o * 128 + f0 * 2) ^ ((o & 7) << 4);
                *(uint2*)(pb + off) = cv.u;
            }
        }
        if (tid < 2 * FOUT) sA[tid] = ag[tid];
    }

    // adj prefetch, tile 0, in A-frag layout: rows w*32+m16 (+16), cols g*8+[0..8)
    const int row0 = w * 32 + m16;
    const int* aprow0 = adjp + row0 * D_ + g * 8;          // advance by +32 per tile
    const int* aprow1 = aprow0 + 16 * D_;
    int4 areg[4];
    areg[0] = *(const int4*)(aprow0);
    areg[1] = *(const int4*)(aprow0 + 4);
    areg[2] = *(const int4*)(aprow1);
    areg[3] = *(const int4*)(aprow1 + 4);
    __syncthreads();   // B1: staged h/W visible to all waves

    // ---------------- phase A: Wh = h @ W via MFMA 16x16x32 f16 ----------------
    f32x4 acc[2][4];
    #pragma unroll
    for (int mt = 0; mt < 2; ++mt)
        #pragma unroll
        for (int nt = 0; nt < 4; ++nt) acc[mt][nt] = (f32x4){0.f, 0.f, 0.f, 0.f};

    #pragma unroll
    for (int kt = 0; kt < 2; ++kt) {
        f16x8 af[2], bf[4];
        #pragma unroll
        for (int mt = 0; mt < 2; ++mt) {
            int row = w * 32 + mt * 16 + m16;
            af[mt] = *(const f16x8*)(xb + ((row * 128 + kt * 64 + g * 16) ^ ((row & 7) << 4)));
        }
        #pragma unroll
        for (int nt = 0; nt < 4; ++nt) {
            int o = nt * 16 + m16;
            bf[nt] = *(const f16x8*)(pb + ((o * 128 + kt * 64 + g * 16) ^ ((o & 7) << 4)));
        }
        #pragma unroll
        for (int mt = 0; mt < 2; ++mt)
            #pragma unroll
            for (int nt = 0; nt < 4; ++nt)
                acc[mt][nt] = __builtin_amdgcn_mfma_f32_16x16x32_f16(af[mt], bf[nt], acc[mt][nt], 0, 0, 0);
    }
    __syncthreads();   // B2: all cross-wave sX/sPt reads done before WhT overwrites sX

    // ---------------- phase B: e_i/e_j via register butterfly; WhT -> sX ----------------
    {
        float a1v[4], a2v[4];
        #pragma unroll
        for (int nt = 0; nt < 4; ++nt) {
            a1v[nt] = sA[nt * 16 + m16];
            a2v[nt] = sA[FOUT + nt * 16 + m16];
        }
        float wmax = -3.0e38f;
        #pragma unroll
        for (int mt = 0; mt < 2; ++mt) {
            #pragma unroll
            for (int r = 0; r < 4; ++r) {
                float ei = 0.f, ej = 0.f;
                #pragma unroll
                for (int nt = 0; nt < 4; ++nt) {
                    float v = acc[mt][nt][r];
                    ei += v * a1v[nt];
                    ej += v * a2v[nt];
                }
                #pragma unroll
                for (int s = 1; s < 16; s <<= 1) {
                    ei += __shfl_xor(ei, s);
                    ej += __shfl_xor(ej, s);
                }
                int row = w * 32 + mt * 16 + g * 4 + r;   // D-frag row (col=lane&15, row=(lane>>4)*4+reg)
                if (m16 == 0) { sEi[row] = ei; sEj[row] = ej; }
                wmax = fmaxf(wmax, ej);
            }
        }
        wmax = fmaxf(wmax, __shfl_xor(wmax, 16));
        wmax = fmaxf(wmax, __shfl_xor(wmax, 32));
        if (lane == 0) sMxW[w] = wmax;

        // write Wh^T f16 into sX: WhT[o][j], 4 consecutive j per (mt,nt) = one 8B write
        #pragma unroll
        for (int mt = 0; mt < 2; ++mt) {
            int j0r = w * 32 + mt * 16 + g * 4;
            #pragma unroll
            for (int nt = 0; nt < 4; ++nt) {
                int o = nt * 16 + m16;
                union { _Float16 h[4]; uint2 u; } cv;
                cv.h[0] = (_Float16)acc[mt][nt][0];
                cv.h[1] = (_Float16)acc[mt][nt][1];
                cv.h[2] = (_Float16)acc[mt][nt][2];
                cv.h[3] = (_Float16)acc[mt][nt][3];
                int off = (o * 256 + j0r * 2) ^ ((o & 7) << 4);
                *(uint2*)(xb + off) = cv.u;
            }
        }
    }
    __syncthreads();   // B3: sEj / sMxW / WhT visible to all waves. Last block barrier.

    // ---------------- phase C: P built in-register in A-frag layout + P @ Wh via MFMA ----------------
    #pragma unroll
    for (int mt = 0; mt < 2; ++mt)
        #pragma unroll
        for (int nt = 0; nt < 4; ++nt) acc[mt][nt] = (f32x4){0.f, 0.f, 0.f, 0.f};

    const float ei0 = sEi[row0];
    const float ei1 = sEi[row0 + 16];
    const float mxj = fmaxf(fmaxf(sMxW[0], sMxW[1]), fmaxf(sMxW[2], sMxW[3]));
    float t0 = ei0 + mxj, t1 = ei1 + mxj;
    const float mi0 = t0 > 0.f ? t0 : ALPHA * t0;   // = max_j leaky(ei0+ej) >= any row-0 entry
    const float mi1 = t1 > 0.f ? t1 : ALPHA * t1;
    float lp0 = 0.f, lp1 = 0.f;

    #pragma unroll
    for (int jt = 0; jt < 4; ++jt) {
        const int j0 = jt * 32;
        // e_j slice for this thread's k-columns (broadcast across the 16-lane group)
        float4 ejA = *(const float4*)&sEj[j0 + g * 8];
        float4 ejB = *(const float4*)&sEj[j0 + g * 8 + 4];
        float ejv[8] = {ejA.x, ejA.y, ejA.z, ejA.w, ejB.x, ejB.y, ejB.z, ejB.w};
        int aa0[8] = {areg[0].x, areg[0].y, areg[0].z, areg[0].w,
                      areg[1].x, areg[1].y, areg[1].z, areg[1].w};
        int aa1[8] = {areg[2].x, areg[2].y, areg[2].z, areg[2].w,
                      areg[3].x, areg[3].y, areg[3].z, areg[3].w};
        f16x8 pa0, pa1;
        #pragma unroll
        for (int q = 0; q < 8; ++q) {
            float e0 = ei0 + ejv[q];
            e0 = e0 > 0.f ? e0 : ALPHA * e0;
            float p0 = (aa0[q] > 0) ? __expf(e0 - mi0) : 0.f;   // in (0,1]
            lp0 += p0;
            pa0[q] = (_Float16)p0;
            float e1 = ei1 + ejv[q];
            e1 = e1 > 0.f ? e1 : ALPHA * e1;
            float p1 = (aa1[q] > 0) ? __expf(e1 - mi1) : 0.f;
            lp1 += p1;
            pa1[q] = (_Float16)p1;
        }
        if (jt < 3) {
            // prefetch next adj tile (overlaps with this tile's MFMA)
            const int* n0 = aprow0 + (jt + 1) * 32;
            const int* n1 = aprow1 + (jt + 1) * 32;
            areg[0] = *(const int4*)(n0);
            areg[1] = *(const int4*)(n0 + 4);
            areg[2] = *(const int4*)(n1);
            areg[3] = *(const int4*)(n1 + 4);
        }

        // MFMA: acc += P[:, j0:j0+32] @ Wh[j0:j0+32, :]  (P already in A-frag regs)
        f16x8 wb[4];
        #pragma unroll
        for (int nt = 0; nt < 4; ++nt) {
            int o = nt * 16 + m16;
            wb[nt] = *(const f16x8*)(xb + ((o * 256 + j0 * 2 + g * 16) ^ ((o & 7) << 4)));
        }
        #pragma unroll
        for (int nt = 0; nt < 4; ++nt) {
            acc[0][nt] = __builtin_amdgcn_mfma_f32_16x16x32_f16(pa0, wb[nt], acc[0][nt], 0, 0, 0);
            acc[1][nt] = __builtin_amdgcn_mfma_f32_16x16x32_f16(pa1, wb[nt], acc[1][nt], 0, 0, 0);
        }
    }

    // row sums: reduce across the 4 g-lane groups (lane bits 4-5), then exchange
    // through sL to the D-layout rows used by the epilogue (same wave only).
    lp0 += __shfl_xor(lp0, 16); lp0 += __shfl_xor(lp0, 32);
    lp1 += __shfl_xor(lp1, 16); lp1 += __shfl_xor(lp1, 32);
    if (g == 0) {
        sL[row0]      = lp0;
        sL[row0 + 16] = lp1;
    }

    // ---------------- epilogue: divide by row sum, write out ----------------
    #pragma unroll
    for (int mtx = 0; mtx < 2; ++mtx) {
        #pragma unroll
        for (int r = 0; r < 4; ++r) {
            int row = w * 32 + mtx * 16 + g * 4 + r;
            float inv = 1.0f / sL[row];
            #pragma unroll
            for (int nt = 0; nt < 4; ++nt)
                outp[row * 64 + nt * 16 + m16] = acc[mtx][nt][r] * inv;
        }
    }
}

extern "C" void kernel_launch(void* const* d_in, const int* in_sizes, int n_in,
                              void* d_out, int out_size, void* d_ws, size_t ws_size,
                              hipStream_t stream) {
    const float* h   = (const float*)d_in[0];
    const int*   adj = (const int*)d_in[1];
    const float* W   = (const float*)d_in[2];
    const float* a   = (const float*)d_in[3];
    float*       out = (float*)d_out;
    gat_kernel<<<dim3(16 * 256), dim3(256), 0, stream>>>(h, adj, W, a, out);
}

// Round 5
// 473.336 us; speedup vs baseline: 1.0057x; 1.0057x over previous
//
#include <hip/hip_runtime.h>

// DynamicGraphAttention: B=16, L=256, D=128, F_IN=64, F_OUT=64
// v9 = v8 restructured as a 2-problem pipelined block: each block processes
// bl0=2*bid and bl1=2*bid+1. h(bl1) global loads are issued right after
// phase-A(bl0) and written to a second LDS buffer during phase-B(bl0); adj(bl1)
// tile0 is prefetched in phase-C(bl0)'s last iteration; W is staged once per
// block. Hides the ~900-cycle HBM h-load + staging latency that every block
// previously ate cold. LDS 43KB -> 3 blocks/CU (= measured occupancy before).
constexpr int D_   = 128;
constexpr int FIN  = 64;
constexpr int FOUT = 64;
constexpr float ALPHA = 0.2f;

typedef _Float16 f16x8 __attribute__((ext_vector_type(8)));
typedef float    f32x4 __attribute__((ext_vector_type(4)));

__global__ __launch_bounds__(256, 4) void gat_kernel(
    const float* __restrict__ hg, const int* __restrict__ adjg,
    const float* __restrict__ Wg, const float* __restrict__ ag,
    float* __restrict__ outg)
{
    // per-problem buffer: phase A = h f16 [d][64] swz((d&7)<<4); B/C = WhT f16 [o][128] swz((o&7)<<4)
    __shared__ __align__(16) unsigned short sX0[128 * 64];   // 16 KB, bl0
    __shared__ __align__(16) unsigned short sX1[128 * 64];   // 16 KB, bl1
    __shared__ __align__(16) unsigned short sPt[64 * 64];    // 8 KB, W^T f16 [o][64] swz (both problems)
    __shared__ __align__(16) float sA[2 * FOUT];
    __shared__ float sEi[D_];
    __shared__ __align__(16) float sEj[D_];
    __shared__ float sL[D_];
    __shared__ float sMxW[4];
    // total ~43 KB -> 3 blocks/CU

    const int tid  = threadIdx.x;
    const int lane = tid & 63;
    const int w    = tid >> 6;      // wave 0..3, owns output rows [w*32, w*32+32)
    const int g    = lane >> 4;     // k-group 0..3
    const int m16  = lane & 15;
    const int row0 = w * 32 + m16;

    const long bl0 = 2 * (long)blockIdx.x;
    const long bl1 = bl0 + 1;
    const float* hp0   = hg   + bl0 * (long)(D_ * FIN);
    const float* hp1   = hg   + bl1 * (long)(D_ * FIN);
    const int*   adjp0 = adjg + bl0 * (long)(D_ * D_);
    const int*   adjp1 = adjg + bl1 * (long)(D_ * D_);
    float*       outp0 = outg + bl0 * (long)(D_ * FOUT);
    float*       outp1 = outg + bl1 * (long)(D_ * FOUT);

    char* xb0 = (char*)sX0;
    char* xb1 = (char*)sX1;
    char* pb  = (char*)sPt;

    f32x4 acc[2][4];
    int4  areg[4];     // adj prefetch registers, carried across phases

    // ---------------- stage: h0 -> sX0, W -> sPt (once), a -> sA ----------------
    {
        const float4* h4 = (const float4*)hp0;
        #pragma unroll
        for (int k = 0; k < 8; ++k) {
            int idx = tid + 256 * k;
            float4 v = h4[idx];
            int row = idx >> 4;
            int f   = (idx & 15) << 2;
            union { _Float16 h[4]; uint2 u; } cv;
            cv.h[0] = (_Float16)v.x; cv.h[1] = (_Float16)v.y;
            cv.h[2] = (_Float16)v.z; cv.h[3] = (_Float16)v.w;
            int off = (row * 128 + f * 2) ^ ((row & 7) << 4);
            *(uint2*)(xb0 + off) = cv.u;
        }
        // W: per-thread 4(f) x 4(o) register transpose, 8B conflict-free writes.
        const int f0 = (tid & 15) * 4;
        const int o0 = (tid >> 4) * 4;
        float4 r0 = *(const float4*)&Wg[(f0 + 0) * 64 + o0];
        float4 r1 = *(const float4*)&Wg[(f0 + 1) * 64 + o0];
        float4 r2 = *(const float4*)&Wg[(f0 + 2) * 64 + o0];
        float4 r3 = *(const float4*)&Wg[(f0 + 3) * 64 + o0];
        float col[4][4] = {{r0.x, r1.x, r2.x, r3.x},
                           {r0.y, r1.y, r2.y, r3.y},
                           {r0.z, r1.z, r2.z, r3.z},
                           {r0.w, r1.w, r2.w, r3.w}};
        #pragma unroll
        for (int c = 0; c < 4; ++c) {
            int o = o0 + c;
            union { _Float16 h[4]; uint2 u; } cv;
            cv.h[0] = (_Float16)col[c][0]; cv.h[1] = (_Float16)col[c][1];
            cv.h[2] = (_Float16)col[c][2]; cv.h[3] = (_Float16)col[c][3];
            int off = (o * 128 + f0 * 2) ^ ((o & 7) << 4);
            *(uint2*)(pb + off) = cv.u;
        }
        if (tid < 2 * FOUT) sA[tid] = ag[tid];
        // adj0 tile0 prefetch (A-frag layout: rows row0/row0+16, cols g*8..g*8+8)
        const int* a0 = adjp0 + row0 * D_ + g * 8;
        areg[0] = *(const int4*)(a0);
        areg[1] = *(const int4*)(a0 + 4);
        areg[2] = *(const int4*)(a0 + 16 * D_);
        areg[3] = *(const int4*)(a0 + 16 * D_ + 4);
    }
    __syncthreads();   // B1: staged h0/W visible to all waves

    // ---------------- phase A: Wh = h @ W via MFMA 16x16x32 f16 ----------------
    auto phaseA = [&](char* xb) {
        #pragma unroll
        for (int mt = 0; mt < 2; ++mt)
            #pragma unroll
            for (int nt = 0; nt < 4; ++nt) acc[mt][nt] = (f32x4){0.f, 0.f, 0.f, 0.f};
        #pragma unroll
        for (int kt = 0; kt < 2; ++kt) {
            f16x8 af[2], bf[4];
            #pragma unroll
            for (int mt = 0; mt < 2; ++mt) {
                int row = w * 32 + mt * 16 + m16;
                af[mt] = *(const f16x8*)(xb + ((row * 128 + kt * 64 + g * 16) ^ ((row & 7) << 4)));
            }
            #pragma unroll
            for (int nt = 0; nt < 4; ++nt) {
                int o = nt * 16 + m16;
                bf[nt] = *(const f16x8*)(pb + ((o * 128 + kt * 64 + g * 16) ^ ((o & 7) << 4)));
            }
            #pragma unroll
            for (int mt = 0; mt < 2; ++mt)
                #pragma unroll
                for (int nt = 0; nt < 4; ++nt)
                    acc[mt][nt] = __builtin_amdgcn_mfma_f32_16x16x32_f16(af[mt], bf[nt], acc[mt][nt], 0, 0, 0);
        }
    };

    // ---------------- phase B: e_i/e_j butterflies; WhT -> xb ----------------
    auto phaseB = [&](char* xb) {
        float a1v[4], a2v[4];
        #pragma unroll
        for (int nt = 0; nt < 4; ++nt) {
            a1v[nt] = sA[nt * 16 + m16];
            a2v[nt] = sA[FOUT + nt * 16 + m16];
        }
        float wmax = -3.0e38f;
        #pragma unroll
        for (int mt = 0; mt < 2; ++mt) {
            #pragma unroll
            for (int r = 0; r < 4; ++r) {
                float ei = 0.f, ej = 0.f;
                #pragma unroll
                for (int nt = 0; nt < 4; ++nt) {
                    float v = acc[mt][nt][r];
                    ei += v * a1v[nt];
                    ej += v * a2v[nt];
                }
                #pragma unroll
                for (int s = 1; s < 16; s <<= 1) {
                    ei += __shfl_xor(ei, s);
                    ej += __shfl_xor(ej, s);
                }
                int row = w * 32 + mt * 16 + g * 4 + r;   // D-frag: col=lane&15, row=(lane>>4)*4+reg
                if (m16 == 0) { sEi[row] = ei; sEj[row] = ej; }
                wmax = fmaxf(wmax, ej);
            }
        }
        wmax = fmaxf(wmax, __shfl_xor(wmax, 16));
        wmax = fmaxf(wmax, __shfl_xor(wmax, 32));
        if (lane == 0) sMxW[w] = wmax;
        #pragma unroll
        for (int mt = 0; mt < 2; ++mt) {
            int j0r = w * 32 + mt * 16 + g * 4;
            #pragma unroll
            for (int nt = 0; nt < 4; ++nt) {
                int o = nt * 16 + m16;
                union { _Float16 h[4]; uint2 u; } cv;
                cv.h[0] = (_Float16)acc[mt][nt][0];
                cv.h[1] = (_Float16)acc[mt][nt][1];
                cv.h[2] = (_Float16)acc[mt][nt][2];
                cv.h[3] = (_Float16)acc[mt][nt][3];
                int off = (o * 256 + j0r * 2) ^ ((o & 7) << 4);
                *(uint2*)(xb + off) = cv.u;
            }
        }
    };

    // ---------------- phase C + epilogue ----------------
    auto phaseC = [&](char* xb, const int* adjp, float* outp, const int* adjp_next) {
        #pragma unroll
        for (int mt = 0; mt < 2; ++mt)
            #pragma unroll
            for (int nt = 0; nt < 4; ++nt) acc[mt][nt] = (f32x4){0.f, 0.f, 0.f, 0.f};
        const float ei0 = sEi[row0];
        const float ei1 = sEi[row0 + 16];
        const float mxj = fmaxf(fmaxf(sMxW[0], sMxW[1]), fmaxf(sMxW[2], sMxW[3]));
        float t0 = ei0 + mxj, t1 = ei1 + mxj;
        const float mi0 = t0 > 0.f ? t0 : ALPHA * t0;
        const float mi1 = t1 > 0.f ? t1 : ALPHA * t1;
        float lp0 = 0.f, lp1 = 0.f;
        const int* aprow0 = adjp + row0 * D_ + g * 8;
        const int* aprow1 = aprow0 + 16 * D_;
        #pragma unroll
        for (int jt = 0; jt < 4; ++jt) {
            const int j0 = jt * 32;
            float4 ejA = *(const float4*)&sEj[j0 + g * 8];
            float4 ejB = *(const float4*)&sEj[j0 + g * 8 + 4];
            float ejv[8] = {ejA.x, ejA.y, ejA.z, ejA.w, ejB.x, ejB.y, ejB.z, ejB.w};
            int aa0[8] = {areg[0].x, areg[0].y, areg[0].z, areg[0].w,
                          areg[1].x, areg[1].y, areg[1].z, areg[1].w};
            int aa1[8] = {areg[2].x, areg[2].y, areg[2].z, areg[2].w,
                          areg[3].x, areg[3].y, areg[3].z, areg[3].w};
            f16x8 pa0, pa1;
            #pragma unroll
            for (int q = 0; q < 8; ++q) {
                float e0 = ei0 + ejv[q];
                e0 = e0 > 0.f ? e0 : ALPHA * e0;
                float p0 = (aa0[q] > 0) ? __expf(e0 - mi0) : 0.f;
                lp0 += p0;
                pa0[q] = (_Float16)p0;
                float e1 = ei1 + ejv[q];
                e1 = e1 > 0.f ? e1 : ALPHA * e1;
                float p1 = (aa1[q] > 0) ? __expf(e1 - mi1) : 0.f;
                lp1 += p1;
                pa1[q] = (_Float16)p1;
            }
            if (jt < 3) {
                const int* n0 = aprow0 + (jt + 1) * 32;
                const int* n1 = aprow1 + (jt + 1) * 32;
                areg[0] = *(const int4*)(n0);
                areg[1] = *(const int4*)(n0 + 4);
                areg[2] = *(const int4*)(n1);
                areg[3] = *(const int4*)(n1 + 4);
            } else if (adjp_next) {
                // prefetch NEXT problem's adj tile0 (hides under last MFMAs + epilogue + barrier)
                const int* n0 = adjp_next + row0 * D_ + g * 8;
                areg[0] = *(const int4*)(n0);
                areg[1] = *(const int4*)(n0 + 4);
                areg[2] = *(const int4*)(n0 + 16 * D_);
                areg[3] = *(const int4*)(n0 + 16 * D_ + 4);
            }
            f16x8 wb[4];
            #pragma unroll
            for (int nt = 0; nt < 4; ++nt) {
                int o = nt * 16 + m16;
                wb[nt] = *(const f16x8*)(xb + ((o * 256 + j0 * 2 + g * 16) ^ ((o & 7) << 4)));
            }
            #pragma unroll
            for (int nt = 0; nt < 4; ++nt) {
                acc[0][nt] = __builtin_amdgcn_mfma_f32_16x16x32_f16(pa0, wb[nt], acc[0][nt], 0, 0, 0);
                acc[1][nt] = __builtin_amdgcn_mfma_f32_16x16x32_f16(pa1, wb[nt], acc[1][nt], 0, 0, 0);
            }
        }
        lp0 += __shfl_xor(lp0, 16); lp0 += __shfl_xor(lp0, 32);
        lp1 += __shfl_xor(lp1, 16); lp1 += __shfl_xor(lp1, 32);
        if (g == 0) {
            sL[row0]      = lp0;
            sL[row0 + 16] = lp1;
        }
        #pragma unroll
        for (int mtx = 0; mtx < 2; ++mtx) {
            #pragma unroll
            for (int r = 0; r < 4; ++r) {
                int row = w * 32 + mtx * 16 + g * 4 + r;
                float inv = 1.0f / sL[row];
                #pragma unroll
                for (int nt = 0; nt < 4; ++nt)
                    outp[row * 64 + nt * 16 + m16] = acc[mtx][nt][r] * inv;
            }
        }
    };

    // ================= problem 0 =================
    phaseA(xb0);
    // issue h1 global loads now: consumed ~a full phase later (latency hidden)
    float4 hreg[8];
    {
        const float4* h4 = (const float4*)hp1;
        #pragma unroll
        for (int k = 0; k < 8; ++k) hreg[k] = h4[tid + 256 * k];
    }
    __syncthreads();   // B2: cross-wave sX0/sPt reads done before WhT0 overwrites sX0
    phaseB(xb0);
    // write h1 -> sX1 (nobody touches sX1 until A1)
    #pragma unroll
    for (int k = 0; k < 8; ++k) {
        int idx = tid + 256 * k;
        float4 v = hreg[k];
        int row = idx >> 4;
        int f   = (idx & 15) << 2;
        union { _Float16 h[4]; uint2 u; } cv;
        cv.h[0] = (_Float16)v.x; cv.h[1] = (_Float16)v.y;
        cv.h[2] = (_Float16)v.z; cv.h[3] = (_Float16)v.w;
        int off = (row * 128 + f * 2) ^ ((row & 7) << 4);
        *(uint2*)(xb1 + off) = cv.u;
    }
    __syncthreads();   // B3: sEj/sMxW/WhT0 visible
    phaseC(xb0, adjp0, outp0, adjp1);   // also prefetches adj1 tile0 into areg

    // ================= problem 1 =================
    __syncthreads();   // B1': sX1 staged + all C0 reads of sEi/sEj/sMxW/sL complete
    phaseA(xb1);
    __syncthreads();   // B2'
    phaseB(xb1);
    __syncthreads();   // B3'
    phaseC(xb1, adjp1, outp1, nullptr);
}

extern "C" void kernel_launch(void* const* d_in, const int* in_sizes, int n_in,
                              void* d_out, int out_size, void* d_ws, size_t ws_size,
                              hipStream_t stream) {
    const float* h   = (const float*)d_in[0];
    const int*   adj = (const int*)d_in[1];
    const float* W   = (const float*)d_in[2];
    const float* a   = (const float*)d_in[3];
    float*       out = (float*)d_out;
    gat_kernel<<<dim3(16 * 256 / 2), dim3(256), 0, stream>>>(h, adj, W, a, out);
}